// Round 2
// baseline (332.195 us; speedup 1.0000x reference)
//
#include <hip/hip_runtime.h>

#define BB   32
#define CINc 64
#define HHc  32
#define WWc  32
#define COc  64
#define KSc  7
#define GGc  8
#define PADc 3
#define CPGc 8
#define NPIX (HHc * WWc)   // 1024

// ---------------- Kernel 1: q/k/v 1x1-conv projections ----------------
// One thread = one pixel of one batch image. Weights read with wave-uniform
// indices -> compiler emits s_load, FMA uses SGPR operand.
__global__ __launch_bounds__(256) void proj_kernel(
    const float* __restrict__ x,
    const float* __restrict__ wqf,   // [64][64]
    const float* __restrict__ wkf,
    const float* __restrict__ wvf,
    float* __restrict__ qmap,        // [B][CO][1024]
    float* __restrict__ kmap,
    float* __restrict__ vmap)
{
    const int b = blockIdx.x >> 2;                       // 4 blocks per batch
    const int p = ((blockIdx.x & 3) << 8) + threadIdx.x; // pixel 0..1023

    const float* xb = x + (size_t)b * CINc * NPIX + p;
    float xr[CINc];
#pragma unroll
    for (int c = 0; c < CINc; ++c)
        xr[c] = xb[c * NPIX];

    const size_t obase = (size_t)b * COc * NPIX + p;
    for (int o = 0; o < COc; ++o) {
        float aq = 0.f, ak = 0.f, av = 0.f;
        const float* wqr = wqf + o * CINc;
        const float* wkr = wkf + o * CINc;
        const float* wvr = wvf + o * CINc;
#pragma unroll
        for (int c = 0; c < CINc; ++c) {
            const float xv = xr[c];
            aq = fmaf(xv, wqr[c], aq);
            ak = fmaf(xv, wkr[c], ak);
            av = fmaf(xv, wvr[c], av);
        }
        qmap[obase + (size_t)o * NPIX] = aq;
        kmap[obase + (size_t)o * NPIX] = ak;
        vmap[obase + (size_t)o * NPIX] = av;
    }
}

// ---------------- Kernel 2: unfold-attention + softmax + mask ----------------
// grid: b(32) x g(8) x row-tile(4); block 256 = 8 rows x 32 cols.
__global__ __launch_bounds__(256) void attn_kernel(
    const float* __restrict__ qmap,
    const float* __restrict__ kmap,
    const float* __restrict__ vmap,
    const float* __restrict__ rel_h,   // [32][7]
    const float* __restrict__ rel_w,   // [32][7]
    const float* __restrict__ cv,      // [8]
    float* __restrict__ out)           // [B][CO][32][32]
{
    const int blk  = blockIdx.x;
    const int tile = blk & 3;
    const int g    = (blk >> 2) & 7;
    const int b    = blk >> 5;

    const int w  = threadIdx.x & 31;
    const int lh = threadIdx.x >> 5;
    const int h  = tile * 8 + lh;

    const int o0 = g * CPGc;
    const bool use_h = (o0 < 32);

    // q for this pixel's group channels
    const float* qb = qmap + ((size_t)b * COc + o0) * NPIX + h * WWc + w;
    float q[CPGc];
#pragma unroll
    for (int c = 0; c < CPGc; ++c) q[c] = qb[(size_t)c * NPIX];

    // qrel[t] = sum_c q_c * rel_c(t)   (t = ki for groups 0-3, kj for 4-7)
    float qrel[KSc];
#pragma unroll
    for (int t = 0; t < KSc; ++t) {
        float s = 0.f;
#pragma unroll
        for (int c = 0; c < CPGc; ++c) {
            const float r = use_h
                ? rel_h[(o0 + c) * KSc + t]
                : rel_w[(o0 - 32 + c) * KSc + t];
            s = fmaf(q[c], r, s);
        }
        qrel[t] = s;
    }

    const float* kb = kmap + ((size_t)b * COc + o0) * NPIX;
    const float* vb = vmap + ((size_t)b * COc + o0) * NPIX;

    // scores
    float sc[KSc * KSc];
    float m = -1e30f;
#pragma unroll
    for (int ki = 0; ki < KSc; ++ki) {
        const int y = h + ki - PADc;
        const bool yin = (y >= 0) && (y < HHc);
#pragma unroll
        for (int kj = 0; kj < KSc; ++kj) {
            const int xx = w + kj - PADc;
            const bool in = yin && (xx >= 0) && (xx < WWc);
            float s = use_h ? qrel[ki] : qrel[kj];
            if (in) {
                const int off = y * WWc + xx;
#pragma unroll
                for (int c = 0; c < CPGc; ++c)
                    s = fmaf(q[c], kb[(size_t)c * NPIX + off], s);
            }
            sc[ki * KSc + kj] = s;
            m = fmaxf(m, s);
        }
    }

    // softmax (unnormalized) fused with attn @ v
    float den = 0.f;
    float acc[CPGc];
#pragma unroll
    for (int c = 0; c < CPGc; ++c) acc[c] = 0.f;

#pragma unroll
    for (int ki = 0; ki < KSc; ++ki) {
        const int y = h + ki - PADc;
        const bool yin = (y >= 0) && (y < HHc);
#pragma unroll
        for (int kj = 0; kj < KSc; ++kj) {
            const int xx = w + kj - PADc;
            const float e = __expf(sc[ki * KSc + kj] - m);
            den += e;
            const bool in = yin && (xx >= 0) && (xx < WWc);
            if (in) {
                const int off = y * WWc + xx;
#pragma unroll
                for (int c = 0; c < CPGc; ++c)
                    acc[c] = fmaf(e, vb[(size_t)c * NPIX + off], acc[c]);
            }
        }
    }

    // adaptive mask (computed exactly; all-ones for Z_INIT=4 but cv is an input)
    const int  r  = min(h, HHc - 1 - h);
    const int  lo = (h <= HHc - 1 - h) ? r : r + 1;
    const int  hi = HHc - 1 - r;
    const bool in_ring = (w >= lo) && (w <= hi);
    const float cvg = cv[g];
    float om = ((float)r - 15.0f + cvg * 16.0f) * (1.0f / 3.0f) + 1.0f;
    om = fminf(fmaxf(om, 0.0f), 1.0f);
    const float maskv = in_ring ? om : 1.0f;

    const float scale = maskv / den;

    float* ob = out + ((size_t)b * COc + o0) * NPIX + h * WWc + w;
#pragma unroll
    for (int c = 0; c < CPGc; ++c)
        ob[(size_t)c * NPIX] = acc[c] * scale;
}

extern "C" void kernel_launch(void* const* d_in, const int* in_sizes, int n_in,
                              void* d_out, int out_size, void* d_ws, size_t ws_size,
                              hipStream_t stream) {
    const float* x     = (const float*)d_in[0];
    const float* wq    = (const float*)d_in[1];
    const float* wk    = (const float*)d_in[2];
    const float* wv    = (const float*)d_in[3];
    const float* rel_h = (const float*)d_in[4];
    const float* rel_w = (const float*)d_in[5];
    const float* cv    = (const float*)d_in[6];
    float* out = (float*)d_out;

    float* wsf  = (float*)d_ws;
    float* qmap = wsf;                       // 2097152 floats
    float* kmap = qmap + 2097152;
    float* vmap = kmap + 2097152;

    proj_kernel<<<128, 256, 0, stream>>>(x, wq, wk, wv, qmap, kmap, vmap);
    attn_kernel<<<1024, 256, 0, stream>>>(qmap, kmap, vmap, rel_h, rel_w, cv, out);
}

// Round 3
// 146.078 us; speedup vs baseline: 2.2741x; 2.2741x over previous
//
#include <hip/hip_runtime.h>

#define BB   32
#define CINc 64
#define HHc  32
#define WWc  32
#define COc  64
#define KSc  7
#define GGc  8
#define PADc 3
#define CPGc 8
#define NPIX (HHc * WWc)   // 1024

// ---------------- Kernel 1: q/k/v 1x1-conv projections ----------------
// grid = B(32) x pixel-tile(4) x o-tile(8) = 1024 blocks, 256 threads.
// Each thread: one pixel, 8 output channels of q,k,v. 16 waves/CU for
// latency hiding; weights via uniform float4 loads (L1/broadcast).
__global__ __launch_bounds__(256) void proj_kernel(
    const float* __restrict__ x,
    const float* __restrict__ wqf,   // [64][64]
    const float* __restrict__ wkf,
    const float* __restrict__ wvf,
    float* __restrict__ qmap,        // [B][CO][1024]
    float* __restrict__ kmap,
    float* __restrict__ vmap)
{
    const int blk = blockIdx.x;
    const int ot  = blk & 7;          // o-tile: 8 channels
    const int pt  = (blk >> 3) & 3;   // pixel tile: 256 pixels
    const int b   = blk >> 5;

    const int p = (pt << 8) + threadIdx.x;

    const float* xb = x + (size_t)b * CINc * NPIX + p;
    float xr[CINc];
#pragma unroll
    for (int c = 0; c < CINc; ++c)
        xr[c] = xb[c * NPIX];

    const int o0 = ot << 3;
    const size_t obase = (size_t)b * COc * NPIX + p;

#pragma unroll
    for (int oi = 0; oi < 8; ++oi) {
        const int o = o0 + oi;
        const float4* wqr = (const float4*)(wqf + o * CINc);
        const float4* wkr = (const float4*)(wkf + o * CINc);
        const float4* wvr = (const float4*)(wvf + o * CINc);
        float aq = 0.f, ak = 0.f, av = 0.f;
#pragma unroll
        for (int c4 = 0; c4 < CINc / 4; ++c4) {
            const float4 wq4 = wqr[c4];
            const float4 wk4 = wkr[c4];
            const float4 wv4 = wvr[c4];
            const float x0 = xr[c4 * 4 + 0];
            const float x1 = xr[c4 * 4 + 1];
            const float x2 = xr[c4 * 4 + 2];
            const float x3 = xr[c4 * 4 + 3];
            aq = fmaf(x0, wq4.x, aq); aq = fmaf(x1, wq4.y, aq);
            aq = fmaf(x2, wq4.z, aq); aq = fmaf(x3, wq4.w, aq);
            ak = fmaf(x0, wk4.x, ak); ak = fmaf(x1, wk4.y, ak);
            ak = fmaf(x2, wk4.z, ak); ak = fmaf(x3, wk4.w, ak);
            av = fmaf(x0, wv4.x, av); av = fmaf(x1, wv4.y, av);
            av = fmaf(x2, wv4.z, av); av = fmaf(x3, wv4.w, av);
        }
        qmap[obase + (size_t)o * NPIX] = aq;
        kmap[obase + (size_t)o * NPIX] = ak;
        vmap[obase + (size_t)o * NPIX] = av;
    }
}

// ---------------- Kernel 2: unfold-attention + softmax + mask ----------------
// grid: b(32) x g(8) x row-tile(4); block 256 = 8 rows x 32 cols.
__global__ __launch_bounds__(256) void attn_kernel(
    const float* __restrict__ qmap,
    const float* __restrict__ kmap,
    const float* __restrict__ vmap,
    const float* __restrict__ rel_h,   // [32][7]
    const float* __restrict__ rel_w,   // [32][7]
    const float* __restrict__ cv,      // [8]
    float* __restrict__ out)           // [B][CO][32][32]
{
    const int blk  = blockIdx.x;
    const int tile = blk & 3;
    const int g    = (blk >> 2) & 7;
    const int b    = blk >> 5;

    const int w  = threadIdx.x & 31;
    const int lh = threadIdx.x >> 5;
    const int h  = tile * 8 + lh;

    const int o0 = g * CPGc;
    const bool use_h = (o0 < 32);

    // q for this pixel's group channels
    const float* qb = qmap + ((size_t)b * COc + o0) * NPIX + h * WWc + w;
    float q[CPGc];
#pragma unroll
    for (int c = 0; c < CPGc; ++c) q[c] = qb[(size_t)c * NPIX];

    // qrel[t] = sum_c q_c * rel_c(t)   (t = ki for groups 0-3, kj for 4-7)
    float qrel[KSc];
#pragma unroll
    for (int t = 0; t < KSc; ++t) {
        float s = 0.f;
#pragma unroll
        for (int c = 0; c < CPGc; ++c) {
            const float r = use_h
                ? rel_h[(o0 + c) * KSc + t]
                : rel_w[(o0 - 32 + c) * KSc + t];
            s = fmaf(q[c], r, s);
        }
        qrel[t] = s;
    }

    const float* kb = kmap + ((size_t)b * COc + o0) * NPIX;
    const float* vb = vmap + ((size_t)b * COc + o0) * NPIX;

    // scores
    float sc[KSc * KSc];
    float m = -1e30f;
#pragma unroll
    for (int ki = 0; ki < KSc; ++ki) {
        const int y = h + ki - PADc;
        const bool yin = (y >= 0) && (y < HHc);
#pragma unroll
        for (int kj = 0; kj < KSc; ++kj) {
            const int xx = w + kj - PADc;
            const bool in = yin && (xx >= 0) && (xx < WWc);
            float s = use_h ? qrel[ki] : qrel[kj];
            if (in) {
                const int off = y * WWc + xx;
#pragma unroll
                for (int c = 0; c < CPGc; ++c)
                    s = fmaf(q[c], kb[(size_t)c * NPIX + off], s);
            }
            sc[ki * KSc + kj] = s;
            m = fmaxf(m, s);
        }
    }

    // softmax (unnormalized) fused with attn @ v
    float den = 0.f;
    float acc[CPGc];
#pragma unroll
    for (int c = 0; c < CPGc; ++c) acc[c] = 0.f;

#pragma unroll
    for (int ki = 0; ki < KSc; ++ki) {
        const int y = h + ki - PADc;
        const bool yin = (y >= 0) && (y < HHc);
#pragma unroll
        for (int kj = 0; kj < KSc; ++kj) {
            const int xx = w + kj - PADc;
            const float e = __expf(sc[ki * KSc + kj] - m);
            den += e;
            const bool in = yin && (xx >= 0) && (xx < WWc);
            if (in) {
                const int off = y * WWc + xx;
#pragma unroll
                for (int c = 0; c < CPGc; ++c)
                    acc[c] = fmaf(e, vb[(size_t)c * NPIX + off], acc[c]);
            }
        }
    }

    // adaptive mask (computed exactly; all-ones for Z_INIT=4 but cv is an input)
    const int  r  = min(h, HHc - 1 - h);
    const int  lo = (h <= HHc - 1 - h) ? r : r + 1;
    const int  hi = HHc - 1 - r;
    const bool in_ring = (w >= lo) && (w <= hi);
    const float cvg = cv[g];
    float om = ((float)r - 15.0f + cvg * 16.0f) * (1.0f / 3.0f) + 1.0f;
    om = fminf(fmaxf(om, 0.0f), 1.0f);
    const float maskv = in_ring ? om : 1.0f;

    const float scale = maskv / den;

    float* ob = out + ((size_t)b * COc + o0) * NPIX + h * WWc + w;
#pragma unroll
    for (int c = 0; c < CPGc; ++c)
        ob[(size_t)c * NPIX] = acc[c] * scale;
}

extern "C" void kernel_launch(void* const* d_in, const int* in_sizes, int n_in,
                              void* d_out, int out_size, void* d_ws, size_t ws_size,
                              hipStream_t stream) {
    const float* x     = (const float*)d_in[0];
    const float* wq    = (const float*)d_in[1];
    const float* wk    = (const float*)d_in[2];
    const float* wv    = (const float*)d_in[3];
    const float* rel_h = (const float*)d_in[4];
    const float* rel_w = (const float*)d_in[5];
    const float* cv    = (const float*)d_in[6];
    float* out = (float*)d_out;

    float* wsf  = (float*)d_ws;
    float* qmap = wsf;                       // 2097152 floats
    float* kmap = qmap + 2097152;
    float* vmap = kmap + 2097152;

    proj_kernel<<<1024, 256, 0, stream>>>(x, wq, wk, wv, qmap, kmap, vmap);
    attn_kernel<<<1024, 256, 0, stream>>>(qmap, kmap, vmap, rel_h, rel_w, cv, out);
}